// Round 9
// baseline (541.109 us; speedup 1.0000x reference)
//
#include <hip/hip_runtime.h>
#include <math.h>

#define NWAY 5
#define NSUP 25
#define NZV  125
#define DF   640
#define NQ   75
#define TPB  320

// =====================================================================
// Fast transform: tf(x) = sign(x) * (g(|x|+1e-5) - g(1e-5)),
//   g(t) = ln(1/t+1)^{-1.3} = exp2(-1.3*log2(log2(1/t+1)) + A),
//   A = -1.3*log2(ln2) = 0.68739628. 4 transcendentals vs reference's 8.
// =====================================================================
__device__ __forceinline__ float gfun(float t) {
  const float l2 = __log2f(__builtin_amdgcn_rcpf(t) + 1.0f);
  return __builtin_amdgcn_exp2f(fmaf(-1.3f, __log2f(l2), 0.68739628f));
}
__device__ __forceinline__ float simple_tf(float x, float Cg) {
  const float s = gfun(fabsf(x) + 1e-5f) - Cg;
  return (x >= 0.0f) ? s : -s;
}

// Constant-lane fp64 broadcast via v_readlane (VALU, off the LDS pipe).
__device__ __forceinline__ double bcastd(double v, const int srclane) {
  const int lo = __builtin_amdgcn_readlane(__double2loint(v), srclane);
  const int hi = __builtin_amdgcn_readlane(__double2hiint(v), srclane);
  return __hiloint2double(hi, lo);
}

// In-place Gauss-Jordan of 25x25 SPD; columns live on lanes BASE..BASE+24.
template <int BASE, int J>
__device__ __forceinline__ void gjp(double (&a)[25], const int lane,
                                    const bool act) {
  const double djj = bcastd(a[J], BASE + J);
  const double pinv = 1.0 / djj;
  if (act) a[J] = ((lane == BASE + J) ? 1.0 : a[J]) * pinv;
#pragma unroll
  for (int r = 0; r < 25; ++r) {
    if (r != J) {
      const double f = bcastd(a[r], BASE + J);
      if (act) a[r] = ((lane == BASE + J) ? 0.0 : a[r]) - f * a[J];
    }
  }
}
template <int BASE, int J = 0>
__device__ __forceinline__ void gjall(double (&a)[25], const int lane,
                                      const bool act) {
  if constexpr (J < 25) {
    gjp<BASE, J>(a, lane, act);
    gjall<BASE, J + 1>(a, lane, act);
  }
}

// Factorize: hv <- row `lane` of Hinv_w (symmetric); wave-0 lanes 32-56
// additionally get Winv = (sum_k Hinv_k)^-1 rows. W buffer aliases GBUF.
__device__ __forceinline__ void factorize(const double* Msh, const double* dd,
                                          double* W, double (&hv)[25],
                                          const int tid, const int lane,
                                          const int w) {
  if (lane < 25) {
#pragma unroll
    for (int j = 0; j < 25; ++j)
      hv[j] = Msh[lane * 26 + j] + ((j == lane) ? dd[lane * 5 + w] : 0.0);
  }
  gjall<0>(hv, lane, true);
  for (int i2 = tid; i2 < 650; i2 += TPB) W[i2] = 0.0;
  __syncthreads();
#pragma unroll
  for (int k = 0; k < 5; ++k) {
    if (w == k && lane < 25) {
#pragma unroll
      for (int j = 0; j < 25; ++j) W[lane * 26 + j] += hv[j];
    }
    __syncthreads();
  }
  if (w == 0) {
    if (lane >= 32 && lane < 57) {
#pragma unroll
      for (int r = 0; r < 25; ++r) hv[r] = W[(lane - 32) * 26 + r];
    }
    gjall<32>(hv, lane, lane >= 32 && lane < 57);
  }
  // next consumer phase begins with its own __syncthreads()
}

// KKT solve. ZRS: rs==0; ZR: rx=rz=ry==0; ACC: accumulate into outputs.
// dyw: scratch for THIS solve's dy (back-substitution must use it, not the
// accumulated dy — that read-after-accumulate was the R8 correctness bug).
template <bool ZRS, bool ZR, bool ACC>
__device__ __forceinline__ void kkt_solve(
    const double* Msh, const double* dd, double* tt, double* c1, double* c2,
    double* vv, double* gg, double* dyw, const double* rx, const double* rs,
    const double* rz, const double* ry, double (&hv)[25], double* dx,
    double* ds, double* dz, double* dy, const int tid, const int lane,
    const int w) {
  if (tid < NZV) {
    double t = ZR ? 0.0 : rz[tid];
    if (!ZRS) t -= rs[tid] / dd[tid];
    tt[tid] = t;
  }
  __syncthreads();
  if (tid < NZV) {
    const int i = tid / 5, k = tid - i * 5;
    double acc = ZR ? 0.0 : -rx[tid];
#pragma unroll
    for (int j = 0; j < 25; ++j) acc += Msh[i * 26 + j] * tt[j * 5 + k];
    c1[tid] = acc;
  } else if (tid >= 128 && tid < 153) {
    const int i = tid - 128;
    double acc = ZR ? 0.0 : -ry[i];
#pragma unroll
    for (int k = 0; k < 5; ++k) acc += tt[i * 5 + k];
    c2[i] = acc;
  }
  __syncthreads();
  if (lane < 25) {
    double acc = 0.0;
#pragma unroll
    for (int j = 0; j < 25; ++j) acc += hv[j] * c1[j * 5 + w];
    vv[lane * 5 + w] = acc;
  }
  __syncthreads();
  if (w == 0) {  // gg then dy in the SAME wave: LDS program order suffices
    if (lane < 25) {
      double acc = -c2[lane];
#pragma unroll
      for (int k = 0; k < 5; ++k) acc += vv[lane * 5 + k];
      gg[lane] = acc;
    }
    if (lane >= 32 && lane < 57) {
      double acc = 0.0;
#pragma unroll
      for (int r = 0; r < 25; ++r) acc += hv[r] * gg[r];
      dyw[lane - 32] = acc;
      if (ACC) dy[lane - 32] += acc; else dy[lane - 32] = acc;
    }
  }
  __syncthreads();
  if (lane < 25) {
    double acc = 0.0;
#pragma unroll
    for (int j = 0; j < 25; ++j) acc += hv[j] * dyw[j];
    const int v = lane * 5 + w;
    const double u = vv[v] - acc;
    const double dzv = dd[v] * u;
    const double dxv = u - tt[v];
    const double dsv = ((ZRS ? 0.0 : -rs[v]) - dzv) / dd[v];
    if (ACC) { dz[v] += dzv; dx[v] += dxv; ds[v] += dsv; }
    else     { dz[v]  = dzv; dx[v]  = dxv; ds[v]  = dsv; }
  }
  __syncthreads();
}

__device__ __forceinline__ double bred(const double* buf, int n, int ismin,
                                       double* SC, const int tid) {
  __syncthreads();
  if (tid < 64) {
    double acc = ismin ? 1e300 : 0.0;
    for (int m = tid; m < n; m += 64) {
      const double v = buf[m];
      acc = ismin ? fmin(acc, v) : (acc + v);
    }
#pragma unroll
    for (int off = 32; off > 0; off >>= 1) {
      const double o = __shfl_xor(acc, off);
      acc = ismin ? fmin(acc, o) : (acc + o);
    }
    if (tid == 0) SC[15] = acc;
  }
  __syncthreads();
  return SC[15];
}

// stage 64 columns of transformed+normalized train rows into GBUF[25][68]
__device__ __forceinline__ void stage_chunk(const float* __restrict__ tb,
                                            const int ch, const bool us,
                                            const float Cg,
                                            const float* invn, float* GBUF,
                                            const int tid) {
  for (int idx = tid; idx < 1600; idx += TPB) {
    const int r = idx >> 6, cc = idx & 63;
    float v = tb[r * DF + (ch << 6) + cc];
    if (us) v = simple_tf(v, Cg);
    GBUF[r * 68 + cc] = v * invn[r];
  }
}

// =====================================================================
// Merged kernel: norms -> chunked Gram -> QP (register Hinv/Winv) -> xf.
// LDS ~27 KB -> 2 blocks/CU target.
// =====================================================================
__global__ void __launch_bounds__(TPB, 2) qp_kernel(
    const float* __restrict__ train, const int* __restrict__ usimple,
    float* __restrict__ xfg) {
  const int b = blockIdx.x;
  const int tid = threadIdx.x;
  const int lane = tid & 63;
  const int w = tid >> 6;
  const bool us = (usimple[0] != 0);
  const float Cg = gfun(1e-5f);

  __shared__ double Msh[650];
  __shared__ __align__(16) unsigned char GBW[6800];  // union: W[650] / GBUF
  __shared__ double x[125], s[125], z[125], rx[125], rz[125], dd[125],
      tt[125], c1[125], vv[125], dxa[125], dsa[125], dza[125], rsc[125];
  __shared__ double yv[25], ry[25], c2[25], gg[25], dya[25], dyw[25];
  __shared__ double SC[16];
  __shared__ float invn[25];
  __shared__ float bxs[125];

  double* W = (double*)GBW;
  float* GBUF = (float*)GBW;
  double hv[25];  // row `lane` of Hinv_w; wave0 lanes 32-56: Winv rows

  const float* tb = train + (size_t)b * NSUP * DF;

  // ---- phase 1: row norms (no FT materialization) ----
#pragma unroll
  for (int jj = 0; jj < 5; ++jj) {
    const int r = w * 5 + jj;
    float ss = 0.0f;
#pragma unroll
    for (int c = 0; c < 10; ++c) {
      float v = tb[r * DF + lane + 64 * c];
      if (us) v = simple_tf(v, Cg);
      ss += v * v;
    }
#pragma unroll
    for (int off = 32; off > 0; off >>= 1) ss += __shfl_xor(ss, off);
    if (lane == 0) invn[r] = 1.0f / fmaxf(sqrtf(ss), 1e-12f);
  }
  __syncthreads();

  // ---- phase 2: chunked Gram, M = FT FT^T + I (fp64 accumulate) ----
  int i1, j1, i2v = 0, j2v = 0;
  {
    int rem = tid, i = 0;
    while (rem >= NSUP - i) { rem -= NSUP - i; ++i; }
    i1 = i; j1 = i + rem;
  }
  if (tid < 5) {
    int rem = 320 + tid, i = 0;
    while (rem >= NSUP - i) { rem -= NSUP - i; ++i; }
    i2v = i; j2v = i + rem;
  }
  double acc1 = 0.0, acc2 = 0.0;
  for (int ch = 0; ch < 10; ++ch) {
    stage_chunk(tb, ch, us, Cg, invn, GBUF, tid);
    __syncthreads();
    {
      const float4* ra = (const float4*)(GBUF + i1 * 68);
      const float4* rb = (const float4*)(GBUF + j1 * 68);
#pragma unroll
      for (int c = 0; c < 16; ++c) {
        float4 av = ra[c], bv = rb[c];
        acc1 += (double)av.x * bv.x + (double)av.y * bv.y +
                (double)av.z * bv.z + (double)av.w * bv.w;
      }
    }
    if (tid < 5) {
      const float4* ra = (const float4*)(GBUF + i2v * 68);
      const float4* rb = (const float4*)(GBUF + j2v * 68);
#pragma unroll
      for (int c = 0; c < 16; ++c) {
        float4 av = ra[c], bv = rb[c];
        acc2 += (double)av.x * bv.x + (double)av.y * bv.y +
                (double)av.z * bv.z + (double)av.w * bv.w;
      }
    }
    __syncthreads();
  }
  if (i1 == j1) acc1 += 1.0;
  Msh[i1 * 26 + j1] = acc1;
  if (i1 != j1) Msh[j1 * 26 + i1] = acc1;
  if (tid < 5) {
    if (i2v == j2v) acc2 += 1.0;   // R8 BUG FIX: pairs 322/324 are diagonal
    Msh[i2v * 26 + j2v] = acc2;
    if (i2v != j2v) Msh[j2v * 26 + i2v] = acc2;
  }

  // ---- phase 3: QP ----
  if (tid < NZV) {
    const int i = tid / 5, k = tid - i * 5;
    const double oh = (k == (i % 5)) ? 1.0 : 0.0;
    rx[tid] = -oh;
    rz[tid] = -0.1 * oh;
    dd[tid] = 1.0;
  } else if (tid >= 128 && tid < 153) {
    ry[tid - 128] = 0.0;
  }
  if (tid == 0) SC[0] = 1e300;
  __syncthreads();

  factorize(Msh, dd, W, hv, tid, lane, w);
  kkt_solve<true, false, false>(Msh, dd, tt, c1, c2, vv, gg, dyw, rx,
                                (const double*)nullptr, rz, ry, hv, x, s, z,
                                yv, tid, lane, w);
  {
    const double ms = bred(s, NZV, 1, SC, tid);
    if (ms < 0.0 && tid < NZV) s[tid] -= (ms - 1.0);
    const double mz = bred(z, NZV, 1, SC, tid);
    if (mz < 0.0 && tid < NZV) z[tid] -= (mz - 1.0);
  }
  if (tid < NZV) bxs[tid] = (float)x[tid];

#pragma unroll 1
  for (int it = 0; it < 3; ++it) {
    __syncthreads();
    if (tid < NZV) {
      const int i = tid / 5, k = tid - i * 5;
      double acc = 0.0;
#pragma unroll
      for (int j = 0; j < 25; ++j) acc += Msh[i * 26 + j] * x[j * 5 + k];
      const double oh = (k == (i % 5)) ? 1.0 : 0.0;
      rx[tid] = yv[i] + z[tid] + acc - oh;
      rz[tid] = x[tid] + s[tid] - 0.1 * oh;
    } else if (tid >= 128 && tid < 153) {
      const int i = tid - 128;
      double acc = 0.0;
#pragma unroll
      for (int k = 0; k < 5; ++k) acc += x[i * 5 + k];
      ry[i] = acc;
    }
    __syncthreads();
    if (tid < 64) {  // consolidated 4-sum reduction
      double s1 = 0, s2 = 0, s3 = 0, s4 = 0;
      for (int m = tid; m < 125; m += 64) {
        s1 += s[m] * z[m];
        s2 += rx[m] * rx[m];
        s3 += rz[m] * rz[m];
      }
      if (tid < 25) s4 = ry[tid] * ry[tid];
#pragma unroll
      for (int off = 32; off > 0; off >>= 1) {
        s1 += __shfl_xor(s1, off);
        s2 += __shfl_xor(s2, off);
        s3 += __shfl_xor(s3, off);
        s4 += __shfl_xor(s4, off);
      }
      if (tid == 0) { SC[2] = s1; SC[3] = s2; SC[4] = s3; SC[5] = s4; }
    }
    __syncthreads();
    const double szsum = SC[2];
    const double mu = fabs(szsum) / 125.0;
    const double res = sqrt(SC[4] + 1e-30) + sqrt(SC[5] + 1e-30) +
                       sqrt(SC[3] + 1e-30) + 125.0 * mu;
    if (tid == 0) {
      if (res < SC[0]) { SC[0] = res; SC[1] = 1.0; } else SC[1] = 0.0;
    }
    __syncthreads();
    if (SC[1] != 0.0 && tid < NZV) bxs[tid] = (float)x[tid];
    if (it == 2) break;
    __syncthreads();

    if (tid < NZV) dd[tid] = z[tid] / s[tid];
    __syncthreads();
    factorize(Msh, dd, W, hv, tid, lane, w);
    kkt_solve<false, false, false>(Msh, dd, tt, c1, c2, vv, gg, dyw, rx, z,
                                   rz, ry, hv, dxa, dsa, dza, dya, tid, lane,
                                   w);
    if (tid < NZV) {
      const double a1 = (dza[tid] < 0.0) ? (-z[tid] / dza[tid]) : 1e12;
      const double a2 = (dsa[tid] < 0.0) ? (-s[tid] / dsa[tid]) : 1e12;
      tt[tid] = fmin(a1, a2);
    }
    const double aff = fmin(bred(tt, NZV, 1, SC, tid), 1.0);
    if (tid < NZV)
      tt[tid] = (s[tid] + aff * dsa[tid]) * (z[tid] + aff * dza[tid]);
    const double num = bred(tt, NZV, 0, SC, tid);
    const double sg = num / szsum;
    const double musig = mu * (sg * sg * sg);
    if (tid < NZV) rsc[tid] = (-musig + dsa[tid] * dza[tid]) / s[tid];
    __syncthreads();
    kkt_solve<false, true, true>(Msh, dd, tt, c1, c2, vv, gg, dyw, rx, rsc,
                                 rz, ry, hv, dxa, dsa, dza, dya, tid, lane,
                                 w);
    if (tid < NZV) {
      const double a1 = (dza[tid] < 0.0) ? (-z[tid] / dza[tid]) : 1e12;
      const double a2 = (dsa[tid] < 0.0) ? (-s[tid] / dsa[tid]) : 1e12;
      tt[tid] = fmin(a1, a2);
    }
    const double al = fmin(0.999 * bred(tt, NZV, 1, SC, tid), 1.0);
    if (tid < NZV) {
      x[tid] += al * dxa[tid];
      s[tid] += al * dsa[tid];
      z[tid] += al * dza[tid];
    } else if (tid >= 128 && tid < 153) {
      const int i = tid - 128;
      yv[i] += al * dya[i];
    }
  }
  __syncthreads();

  // ---- phase 4: xf[w][d] = sum_s bx[s,w] * FT[s][d], chunked ----
  float xs[25];
#pragma unroll
  for (int s_ = 0; s_ < 25; ++s_) xs[s_] = bxs[s_ * 5 + w];
  for (int ch = 0; ch < 10; ++ch) {
    stage_chunk(tb, ch, us, Cg, invn, GBUF, tid);
    __syncthreads();
    float acc = 0.0f;
#pragma unroll
    for (int s_ = 0; s_ < 25; ++s_) acc += xs[s_] * GBUF[s_ * 68 + lane];
    xfg[((size_t)b * NWAY + w) * DF + (ch << 6) + lane] = acc;
    __syncthreads();
  }
}

// =====================================================================
// Output kernel: out[q][w2] = (fq_q/|fq_q|) . xf[w2]. fp32 accumulation;
// cheap transform. Grid B*3, LDS 12.8 KB.
// =====================================================================
__global__ void __launch_bounds__(TPB) out_kernel(
    const float* __restrict__ test, const int* __restrict__ usimple,
    const float* __restrict__ xfg, float* __restrict__ out) {
  const int bb = blockIdx.x;
  const int b = bb / 3;
  const int t = bb - 3 * b;
  const int tid = threadIdx.x;
  const int lane = tid & 63;
  const int w = tid >> 6;
  const bool us = (usimple[0] != 0);
  const float Cg = gfun(1e-5f);

  __shared__ float xfs[NWAY * DF];
  for (int i = tid; i < NWAY * DF; i += TPB)
    xfs[i] = xfg[(size_t)b * NWAY * DF + i];
  __syncthreads();

  const float* qb = test + (size_t)b * NQ * DF;
#pragma unroll
  for (int jj = 0; jj < 5; ++jj) {
    const int q = 25 * t + w + 5 * jj;
    const float* qr = qb + (size_t)q * DF;
    float nrm = 0.0f, a0 = 0.0f, a1 = 0.0f, a2 = 0.0f, a3 = 0.0f, a4 = 0.0f;
#pragma unroll
    for (int c = 0; c < 10; ++c) {
      const int d = lane + 64 * c;
      float v = qr[d];
      if (us) v = simple_tf(v, Cg);
      nrm += v * v;
      a0 += v * xfs[0 * DF + d];
      a1 += v * xfs[1 * DF + d];
      a2 += v * xfs[2 * DF + d];
      a3 += v * xfs[3 * DF + d];
      a4 += v * xfs[4 * DF + d];
    }
#pragma unroll
    for (int off = 32; off > 0; off >>= 1) {
      nrm += __shfl_xor(nrm, off);
      a0 += __shfl_xor(a0, off);
      a1 += __shfl_xor(a1, off);
      a2 += __shfl_xor(a2, off);
      a3 += __shfl_xor(a3, off);
      a4 += __shfl_xor(a4, off);
    }
    if (lane == 0) {
      const float sc = 1.0f / fmaxf(sqrtf(nrm), 1e-12f);
      float* op = out + ((size_t)b * NQ + q) * 5;
      op[0] = a0 * sc;
      op[1] = a1 * sc;
      op[2] = a2 * sc;
      op[3] = a3 * sc;
      op[4] = a4 * sc;
    }
  }
}

// =====================================================================
extern "C" void kernel_launch(void* const* d_in, const int* in_sizes, int n_in,
                              void* d_out, int out_size, void* d_ws,
                              size_t ws_size, hipStream_t stream) {
  const float* ftest = (const float*)d_in[0];
  const float* ftrain = (const float*)d_in[1];
  const int* usimple = (const int*)d_in[4];
  float* out = (float*)d_out;
  const int B = in_sizes[1] / (NSUP * DF);

  float* xfg = (float*)d_ws;  // B * 5 * 640 floats

  qp_kernel<<<dim3(B), dim3(TPB), 0, stream>>>(ftrain, usimple, xfg);
  out_kernel<<<dim3(B * 3), dim3(TPB), 0, stream>>>(ftest, usimple, xfg, out);
}

// Round 10
// 446.841 us; speedup vs baseline: 1.2110x; 1.2110x over previous
//
#include <hip/hip_runtime.h>
#include <math.h>

#define NWAY 5
#define NSUP 25
#define NZV  125
#define DF   640
#define NQ   75
#define TPB  640   // two batches per block: waves 0-4 batch A, 5-9 batch B

// =====================================================================
// Fast transform: tf(x) = sign(x) * (g(|x|+1e-5) - g(1e-5)),
//   g(t) = ln(1/t+1)^{-1.3} = exp2(-1.3*log2(log2(1/t+1)) + A),
//   A = -1.3*log2(ln2) = 0.68739628. 4 transcendentals vs reference's 8.
// =====================================================================
__device__ __forceinline__ float gfun(float t) {
  const float l2 = __log2f(__builtin_amdgcn_rcpf(t) + 1.0f);
  return __builtin_amdgcn_exp2f(fmaf(-1.3f, __log2f(l2), 0.68739628f));
}
__device__ __forceinline__ float simple_tf(float x, float Cg) {
  const float s = gfun(fabsf(x) + 1e-5f) - Cg;
  return (x >= 0.0f) ? s : -s;
}

// Constant-lane fp64 broadcast via v_readlane (VALU, off the LDS pipe).
__device__ __forceinline__ double bcastd(double v, const int srclane) {
  const int lo = __builtin_amdgcn_readlane(__double2loint(v), srclane);
  const int hi = __builtin_amdgcn_readlane(__double2hiint(v), srclane);
  return __hiloint2double(hi, lo);
}

// In-place Gauss-Jordan of 25x25 SPD; columns live on lanes BASE..BASE+24.
template <int BASE, int J>
__device__ __forceinline__ void gjp(double (&a)[25], const int lane,
                                    const bool act) {
  const double djj = bcastd(a[J], BASE + J);
  const double pinv = 1.0 / djj;
  if (act) a[J] = ((lane == BASE + J) ? 1.0 : a[J]) * pinv;
#pragma unroll
  for (int r = 0; r < 25; ++r) {
    if (r != J) {
      const double f = bcastd(a[r], BASE + J);
      if (act) a[r] = ((lane == BASE + J) ? 0.0 : a[r]) - f * a[J];
    }
  }
}
template <int BASE, int J = 0>
__device__ __forceinline__ void gjall(double (&a)[25], const int lane,
                                      const bool act) {
  if constexpr (J < 25) {
    gjp<BASE, J>(a, lane, act);
    gjall<BASE, J + 1>(a, lane, act);
  }
}

// Factorize (per half): hv <- row `lane` of Hinv_w; this half's wave-0
// lanes 32-56 additionally get Winv = (sum_k Hinv_k)^-1 rows.
__device__ __forceinline__ void factorize(const double* Msh, const double* dd,
                                          double* W, double (&hv)[25],
                                          const int tl, const int lane,
                                          const int w) {
  if (lane < 25) {
#pragma unroll
    for (int j = 0; j < 25; ++j)
      hv[j] = Msh[lane * 26 + j] + ((j == lane) ? dd[lane * 5 + w] : 0.0);
  }
  gjall<0>(hv, lane, true);
  for (int i2 = tl; i2 < 650; i2 += 320) W[i2] = 0.0;
  __syncthreads();
#pragma unroll
  for (int k = 0; k < 5; ++k) {
    if (w == k && lane < 25) {
#pragma unroll
      for (int j = 0; j < 25; ++j) W[lane * 26 + j] += hv[j];
    }
    __syncthreads();
  }
  if (w == 0) {
    if (lane >= 32 && lane < 57) {
#pragma unroll
      for (int r = 0; r < 25; ++r) hv[r] = W[(lane - 32) * 26 + r];
    }
    gjall<32>(hv, lane, lane >= 32 && lane < 57);
  }
  // next consumer phase begins with its own __syncthreads()
}

// KKT solve (per half). ZRS: rs==0; ZR: rx=rz=ry==0; ACC: accumulate.
// dyw: scratch for THIS solve's dy (back-substitution uses it, not the
// accumulated dy).
template <bool ZRS, bool ZR, bool ACC>
__device__ __forceinline__ void kkt_solve(
    const double* Msh, const double* dd, double* tt, double* c1, double* c2,
    double* vv, double* gg, double* dyw, const double* rx, const double* rs,
    const double* rz, const double* ry, double (&hv)[25], double* dx,
    double* ds, double* dz, double* dy, const int tl, const int lane,
    const int w) {
  if (tl < NZV) {
    double t = ZR ? 0.0 : rz[tl];
    if (!ZRS) t -= rs[tl] / dd[tl];
    tt[tl] = t;
  }
  __syncthreads();
  if (tl < NZV) {
    const int i = tl / 5, k = tl - i * 5;
    double acc = ZR ? 0.0 : -rx[tl];
#pragma unroll
    for (int j = 0; j < 25; ++j) acc += Msh[i * 26 + j] * tt[j * 5 + k];
    c1[tl] = acc;
  } else if (tl >= 128 && tl < 153) {
    const int i = tl - 128;
    double acc = ZR ? 0.0 : -ry[i];
#pragma unroll
    for (int k = 0; k < 5; ++k) acc += tt[i * 5 + k];
    c2[i] = acc;
  }
  __syncthreads();
  if (lane < 25) {
    double acc = 0.0;
#pragma unroll
    for (int j = 0; j < 25; ++j) acc += hv[j] * c1[j * 5 + w];
    vv[lane * 5 + w] = acc;
  }
  __syncthreads();
  if (w == 0) {  // gg then dy in the SAME wave: LDS program order suffices
    if (lane < 25) {
      double acc = -c2[lane];
#pragma unroll
      for (int k = 0; k < 5; ++k) acc += vv[lane * 5 + k];
      gg[lane] = acc;
    }
    if (lane >= 32 && lane < 57) {
      double acc = 0.0;
#pragma unroll
      for (int r = 0; r < 25; ++r) acc += hv[r] * gg[r];
      dyw[lane - 32] = acc;
      if (ACC) dy[lane - 32] += acc; else dy[lane - 32] = acc;
    }
  }
  __syncthreads();
  if (lane < 25) {
    double acc = 0.0;
#pragma unroll
    for (int j = 0; j < 25; ++j) acc += hv[j] * dyw[j];
    const int v = lane * 5 + w;
    const double u = vv[v] - acc;
    const double dzv = dd[v] * u;
    const double dxv = u - tt[v];
    const double dsv = ((ZRS ? 0.0 : -rs[v]) - dzv) / dd[v];
    if (ACC) { dz[v] += dzv; dx[v] += dxv; ds[v] += dsv; }
    else     { dz[v]  = dzv; dx[v]  = dxv; ds[v]  = dsv; }
  }
  __syncthreads();
}

// Per-half block reduction: first wave of the half reduces buf[0..n).
__device__ __forceinline__ double bred(const double* buf, int n, int ismin,
                                       double* SCh, const int w,
                                       const int lane) {
  __syncthreads();
  if (w == 0) {
    double acc = ismin ? 1e300 : 0.0;
    for (int m = lane; m < n; m += 64) {
      const double v = buf[m];
      acc = ismin ? fmin(acc, v) : (acc + v);
    }
#pragma unroll
    for (int off = 32; off > 0; off >>= 1) {
      const double o = __shfl_xor(acc, off);
      acc = ismin ? fmin(acc, o) : (acc + o);
    }
    if (lane == 0) SCh[15] = acc;
  }
  __syncthreads();
  return SCh[15];
}

// stage 64 columns of transformed+normalized train rows into GBUF[25][68]
__device__ __forceinline__ void stage_chunk(const float* __restrict__ tb,
                                            const int ch, const bool us,
                                            const float Cg,
                                            const float* invn, float* GBUF,
                                            const int tl) {
  for (int idx = tl; idx < 1600; idx += 320) {
    const int r = idx >> 6, cc = idx & 63;
    float v = tb[r * DF + (ch << 6) + cc];
    if (us) v = simple_tf(v, Cg);
    GBUF[r * 68 + cc] = v * invn[r];
  }
}

// =====================================================================
// qp_kernel: TWO batches per 640-thread block (waves 0-4 / 5-9). Both
// halves run the identical barrier sequence on per-half state. Grid
// B/2 = 256 -> one block round per CU (was two), 10 waves/CU resident.
// =====================================================================
__global__ void __launch_bounds__(TPB, 2) qp_kernel(
    const float* __restrict__ train, const int* __restrict__ usimple,
    float* __restrict__ xfg, const int B) {
  const int tid = threadIdx.x;
  const int half = tid >= 320 ? 1 : 0;
  const int tl = tid - 320 * half;
  const int lane = tid & 63;
  const int w = tl >> 6;
  const int bb = 2 * blockIdx.x + half;
  const bool live = bb < B;
  const bool us = (usimple[0] != 0);
  const float Cg = gfun(1e-5f);

  __shared__ double Msh_[2][650];
  __shared__ __align__(16) unsigned char GBW_[2][6800];
  __shared__ double x_[2][125], s_[2][125], z_[2][125], rx_[2][125],
      rz_[2][125], dd_[2][125], tt_[2][125], c1_[2][125], vv_[2][125],
      dxa_[2][125], dsa_[2][125], dza_[2][125], rsc_[2][125];
  __shared__ double yv_[2][25], ry_[2][25], c2_[2][25], gg_[2][25],
      dya_[2][25], dyw_[2][25];
  __shared__ double SC_[2][16];
  __shared__ float invn_[2][25];
  __shared__ float bxs_[2][125];

  double* Msh = Msh_[half];
  double* W = (double*)GBW_[half];
  float* GBUF = (float*)GBW_[half];
  double* x = x_[half];
  double* s = s_[half];
  double* z = z_[half];
  double* rx = rx_[half];
  double* rz = rz_[half];
  double* dd = dd_[half];
  double* tt = tt_[half];
  double* c1 = c1_[half];
  double* vv = vv_[half];
  double* dxa = dxa_[half];
  double* dsa = dsa_[half];
  double* dza = dza_[half];
  double* rsc = rsc_[half];
  double* yv = yv_[half];
  double* ry = ry_[half];
  double* c2 = c2_[half];
  double* gg = gg_[half];
  double* dya = dya_[half];
  double* dyw = dyw_[half];
  double* SC = SC_[half];
  float* invn = invn_[half];
  float* bxs = bxs_[half];
  double hv[25];

  const float* tb = train + (size_t)(live ? bb : 0) * NSUP * DF;

  // ---- phase 1: row norms ----
#pragma unroll
  for (int jj = 0; jj < 5; ++jj) {
    const int r = w * 5 + jj;
    float ss = 0.0f;
#pragma unroll
    for (int c = 0; c < 10; ++c) {
      float v = tb[r * DF + lane + 64 * c];
      if (us) v = simple_tf(v, Cg);
      ss += v * v;
    }
#pragma unroll
    for (int off = 32; off > 0; off >>= 1) ss += __shfl_xor(ss, off);
    if (lane == 0) invn[r] = 1.0f / fmaxf(sqrtf(ss), 1e-12f);
  }
  __syncthreads();

  // ---- phase 2: chunked Gram, M = FT FT^T + I (fp64 accumulate) ----
  int i1, j1, i2v = 0, j2v = 0;
  {
    int rem = tl, i = 0;
    while (rem >= NSUP - i) { rem -= NSUP - i; ++i; }
    i1 = i; j1 = i + rem;
  }
  if (tl < 5) {
    int rem = 320 + tl, i = 0;
    while (rem >= NSUP - i) { rem -= NSUP - i; ++i; }
    i2v = i; j2v = i + rem;
  }
  double acc1 = 0.0, acc2 = 0.0;
  for (int ch = 0; ch < 10; ++ch) {
    stage_chunk(tb, ch, us, Cg, invn, GBUF, tl);
    __syncthreads();
    {
      const float4* ra = (const float4*)(GBUF + i1 * 68);
      const float4* rb = (const float4*)(GBUF + j1 * 68);
#pragma unroll
      for (int c = 0; c < 16; ++c) {
        float4 av = ra[c], bv = rb[c];
        acc1 += (double)av.x * bv.x + (double)av.y * bv.y +
                (double)av.z * bv.z + (double)av.w * bv.w;
      }
    }
    if (tl < 5) {
      const float4* ra = (const float4*)(GBUF + i2v * 68);
      const float4* rb = (const float4*)(GBUF + j2v * 68);
#pragma unroll
      for (int c = 0; c < 16; ++c) {
        float4 av = ra[c], bv = rb[c];
        acc2 += (double)av.x * bv.x + (double)av.y * bv.y +
                (double)av.z * bv.z + (double)av.w * bv.w;
      }
    }
    __syncthreads();
  }
  if (i1 == j1) acc1 += 1.0;
  Msh[i1 * 26 + j1] = acc1;
  if (i1 != j1) Msh[j1 * 26 + i1] = acc1;
  if (tl < 5) {
    if (i2v == j2v) acc2 += 1.0;   // pairs 322/324 are diagonal
    Msh[i2v * 26 + j2v] = acc2;
    if (i2v != j2v) Msh[j2v * 26 + i2v] = acc2;
  }

  // ---- phase 3: QP ----
  if (tl < NZV) {
    const int i = tl / 5, k = tl - i * 5;
    const double oh = (k == (i % 5)) ? 1.0 : 0.0;
    rx[tl] = -oh;
    rz[tl] = -0.1 * oh;
    dd[tl] = 1.0;
  } else if (tl >= 128 && tl < 153) {
    ry[tl - 128] = 0.0;
  }
  if (tl == 0) SC[0] = 1e300;
  __syncthreads();

  factorize(Msh, dd, W, hv, tl, lane, w);
  kkt_solve<true, false, false>(Msh, dd, tt, c1, c2, vv, gg, dyw, rx,
                                (const double*)nullptr, rz, ry, hv, x, s, z,
                                yv, tl, lane, w);
  {
    const double ms = bred(s, NZV, 1, SC, w, lane);
    if (ms < 0.0 && tl < NZV) s[tl] -= (ms - 1.0);
    const double mz = bred(z, NZV, 1, SC, w, lane);
    if (mz < 0.0 && tl < NZV) z[tl] -= (mz - 1.0);
  }
  if (tl < NZV) bxs[tl] = (float)x[tl];

#pragma unroll 1
  for (int it = 0; it < 3; ++it) {
    __syncthreads();
    if (tl < NZV) {
      const int i = tl / 5, k = tl - i * 5;
      double acc = 0.0;
#pragma unroll
      for (int j = 0; j < 25; ++j) acc += Msh[i * 26 + j] * x[j * 5 + k];
      const double oh = (k == (i % 5)) ? 1.0 : 0.0;
      rx[tl] = yv[i] + z[tl] + acc - oh;
      rz[tl] = x[tl] + s[tl] - 0.1 * oh;
    } else if (tl >= 128 && tl < 153) {
      const int i = tl - 128;
      double acc = 0.0;
#pragma unroll
      for (int k = 0; k < 5; ++k) acc += x[i * 5 + k];
      ry[i] = acc;
    }
    __syncthreads();
    if (w == 0) {  // per-half consolidated 4-sum reduction (first wave)
      double s1 = 0, s2 = 0, s3 = 0, s4 = 0;
      for (int m = lane; m < 125; m += 64) {
        s1 += s[m] * z[m];
        s2 += rx[m] * rx[m];
        s3 += rz[m] * rz[m];
      }
      if (lane < 25) s4 = ry[lane] * ry[lane];
#pragma unroll
      for (int off = 32; off > 0; off >>= 1) {
        s1 += __shfl_xor(s1, off);
        s2 += __shfl_xor(s2, off);
        s3 += __shfl_xor(s3, off);
        s4 += __shfl_xor(s4, off);
      }
      if (lane == 0) { SC[2] = s1; SC[3] = s2; SC[4] = s3; SC[5] = s4; }
    }
    __syncthreads();
    const double szsum = SC[2];
    const double mu = fabs(szsum) / 125.0;
    const double res = sqrt(SC[4] + 1e-30) + sqrt(SC[5] + 1e-30) +
                       sqrt(SC[3] + 1e-30) + 125.0 * mu;
    if (tl == 0) {
      if (res < SC[0]) { SC[0] = res; SC[1] = 1.0; } else SC[1] = 0.0;
    }
    __syncthreads();
    if (SC[1] != 0.0 && tl < NZV) bxs[tl] = (float)x[tl];
    if (it == 2) break;
    __syncthreads();

    if (tl < NZV) dd[tl] = z[tl] / s[tl];
    __syncthreads();
    factorize(Msh, dd, W, hv, tl, lane, w);
    kkt_solve<false, false, false>(Msh, dd, tt, c1, c2, vv, gg, dyw, rx, z,
                                   rz, ry, hv, dxa, dsa, dza, dya, tl, lane,
                                   w);
    if (tl < NZV) {
      const double a1 = (dza[tl] < 0.0) ? (-z[tl] / dza[tl]) : 1e12;
      const double a2 = (dsa[tl] < 0.0) ? (-s[tl] / dsa[tl]) : 1e12;
      tt[tl] = fmin(a1, a2);
    }
    const double aff = fmin(bred(tt, NZV, 1, SC, w, lane), 1.0);
    if (tl < NZV)
      tt[tl] = (s[tl] + aff * dsa[tl]) * (z[tl] + aff * dza[tl]);
    const double num = bred(tt, NZV, 0, SC, w, lane);
    const double sg = num / szsum;
    const double musig = mu * (sg * sg * sg);
    if (tl < NZV) rsc[tl] = (-musig + dsa[tl] * dza[tl]) / s[tl];
    __syncthreads();
    kkt_solve<false, true, true>(Msh, dd, tt, c1, c2, vv, gg, dyw, rx, rsc,
                                 rz, ry, hv, dxa, dsa, dza, dya, tl, lane,
                                 w);
    if (tl < NZV) {
      const double a1 = (dza[tl] < 0.0) ? (-z[tl] / dza[tl]) : 1e12;
      const double a2 = (dsa[tl] < 0.0) ? (-s[tl] / dsa[tl]) : 1e12;
      tt[tl] = fmin(a1, a2);
    }
    const double al = fmin(0.999 * bred(tt, NZV, 1, SC, w, lane), 1.0);
    if (tl < NZV) {
      x[tl] += al * dxa[tl];
      s[tl] += al * dsa[tl];
      z[tl] += al * dza[tl];
    } else if (tl >= 128 && tl < 153) {
      const int i = tl - 128;
      yv[i] += al * dya[i];
    }
  }
  __syncthreads();

  // ---- phase 4: xf[w][d] = sum_s bx[s,w] * FT[s][d], chunked ----
  float xs[25];
#pragma unroll
  for (int s_ = 0; s_ < 25; ++s_) xs[s_] = bxs[s_ * 5 + w];
  for (int ch = 0; ch < 10; ++ch) {
    stage_chunk(tb, ch, us, Cg, invn, GBUF, tl);
    __syncthreads();
    float acc = 0.0f;
#pragma unroll
    for (int s_ = 0; s_ < 25; ++s_) acc += xs[s_] * GBUF[s_ * 68 + lane];
    if (live)
      xfg[((size_t)bb * NWAY + w) * DF + (ch << 6) + lane] = acc;
    __syncthreads();
  }
}

// =====================================================================
// Output kernel: one block per batch, 640 threads = 10 waves; wave u
// handles queries u, u+10, ... (7-8 each). Grid 512 -> 2 rounds/CU
// (was 6), 10 waves resident.
// =====================================================================
__global__ void __launch_bounds__(640) out_kernel(
    const float* __restrict__ test, const int* __restrict__ usimple,
    const float* __restrict__ xfg, float* __restrict__ out) {
  const int b = blockIdx.x;
  const int tid = threadIdx.x;
  const int lane = tid & 63;
  const int u = tid >> 6;   // 0..9
  const bool us = (usimple[0] != 0);
  const float Cg = gfun(1e-5f);

  __shared__ float xfs[NWAY * DF];
  for (int i = tid; i < NWAY * DF; i += 640)
    xfs[i] = xfg[(size_t)b * NWAY * DF + i];
  __syncthreads();

  const float* qb = test + (size_t)b * NQ * DF;
#pragma unroll 1
  for (int jj = 0; jj < 8; ++jj) {
    const int q = u + 10 * jj;
    if (q >= NQ) break;
    const float* qr = qb + (size_t)q * DF;
    float nrm = 0.0f, a0 = 0.0f, a1 = 0.0f, a2 = 0.0f, a3 = 0.0f, a4 = 0.0f;
#pragma unroll
    for (int c = 0; c < 10; ++c) {
      const int d = lane + 64 * c;
      float v = qr[d];
      if (us) v = simple_tf(v, Cg);
      nrm += v * v;
      a0 += v * xfs[0 * DF + d];
      a1 += v * xfs[1 * DF + d];
      a2 += v * xfs[2 * DF + d];
      a3 += v * xfs[3 * DF + d];
      a4 += v * xfs[4 * DF + d];
    }
#pragma unroll
    for (int off = 32; off > 0; off >>= 1) {
      nrm += __shfl_xor(nrm, off);
      a0 += __shfl_xor(a0, off);
      a1 += __shfl_xor(a1, off);
      a2 += __shfl_xor(a2, off);
      a3 += __shfl_xor(a3, off);
      a4 += __shfl_xor(a4, off);
    }
    if (lane == 0) {
      const float sc = 1.0f / fmaxf(sqrtf(nrm), 1e-12f);
      float* op = out + ((size_t)b * NQ + q) * 5;
      op[0] = a0 * sc;
      op[1] = a1 * sc;
      op[2] = a2 * sc;
      op[3] = a3 * sc;
      op[4] = a4 * sc;
    }
  }
}

// =====================================================================
extern "C" void kernel_launch(void* const* d_in, const int* in_sizes, int n_in,
                              void* d_out, int out_size, void* d_ws,
                              size_t ws_size, hipStream_t stream) {
  const float* ftest = (const float*)d_in[0];
  const float* ftrain = (const float*)d_in[1];
  const int* usimple = (const int*)d_in[4];
  float* out = (float*)d_out;
  const int B = in_sizes[1] / (NSUP * DF);

  float* xfg = (float*)d_ws;  // B * 5 * 640 floats

  qp_kernel<<<dim3((B + 1) / 2), dim3(TPB), 0, stream>>>(ftrain, usimple,
                                                         xfg, B);
  out_kernel<<<dim3(B), dim3(640), 0, stream>>>(ftest, usimple, xfg, out);
}